// Round 1
// baseline (210.030 us; speedup 1.0000x reference)
//
#include <hip/hip_runtime.h>
#include <hip/hip_bf16.h>
#include <math.h>

// Problem constants (x: [32, 256, 56, 56] fp32)
#define B_  32
#define C_  256
#define H_  56
#define W_  56
#define HW_ (H_ * W_)          // 3136
#define BHW_ (B_ * HW_)        // 100352

// ---------------------------------------------------------------------------
// Kernel 1: channel-wise mean + max.
// Grid: BHW_/64 blocks of 256 threads. Each block covers 64 consecutive hw
// positions (3136 % 64 == 0, so a block never spans a batch boundary).
// Thread layout: tx = hw lane (0..63), ty = channel partition (0..3).
// pool layout: [B, 2, HW] — channel 0 = avg, channel 1 = max.
// ---------------------------------------------------------------------------
__global__ __launch_bounds__(256) void sa_reduce_kernel(
    const float* __restrict__ x, float* __restrict__ pool) {
  const int tx = threadIdx.x & 63;
  const int ty = threadIdx.x >> 6;
  const long base_pos = (long)blockIdx.x * 64;   // index into B*HW
  const int b = (int)(base_pos / HW_);
  const int hw0 = (int)(base_pos % HW_);
  const float* xp = x + (long)b * C_ * HW_ + hw0 + tx;

  float s = 0.f;
  float m = -INFINITY;
#pragma unroll 8
  for (int c = ty; c < C_; c += 4) {
    float v = xp[(long)c * HW_];
    s += v;
    m = fmaxf(m, v);
  }

  __shared__ float ssum[4][64];
  __shared__ float smax[4][64];
  ssum[ty][tx] = s;
  smax[ty][tx] = m;
  __syncthreads();

  if (ty == 0) {
    float S = ssum[0][tx] + ssum[1][tx] + ssum[2][tx] + ssum[3][tx];
    float M = fmaxf(fmaxf(smax[0][tx], smax[1][tx]),
                    fmaxf(smax[2][tx], smax[3][tx]));
    float* pb = pool + (long)b * 2 * HW_ + hw0 + tx;
    pb[0]   = S * (1.0f / (float)C_);  // avg
    pb[HW_] = M;                       // max
  }
}

// ---------------------------------------------------------------------------
// Kernel 2: 7x7 SAME conv (2 in-ch -> 1 out-ch) + sigmoid.
// One thread per (b, hw). Weight is 98 floats (OIHW, o=0): w[(ic*7+kh)*7+kw].
// ---------------------------------------------------------------------------
__global__ __launch_bounds__(256) void sa_conv_kernel(
    const float* __restrict__ pool, const float* __restrict__ wt,
    float* __restrict__ gate) {
  int idx = blockIdx.x * blockDim.x + threadIdx.x;
  if (idx >= BHW_) return;
  const int b = idx / HW_;
  const int hw = idx % HW_;
  const int h = hw / W_;
  const int w = hw % W_;

  const float* p = pool + (long)b * 2 * HW_;
  float acc = 0.f;
#pragma unroll
  for (int ic = 0; ic < 2; ++ic) {
#pragma unroll
    for (int kh = 0; kh < 7; ++kh) {
      const int ih = h + kh - 3;
      if (ih < 0 || ih >= H_) continue;
      const float* row = p + ic * HW_ + ih * W_;
      const float* wr = wt + (ic * 7 + kh) * 7;
#pragma unroll
      for (int kw = 0; kw < 7; ++kw) {
        const int iw = w + kw - 3;
        if (iw < 0 || iw >= W_) continue;
        acc = fmaf(row[iw], wr[kw], acc);
      }
    }
  }
  gate[idx] = 1.0f / (1.0f + __expf(-acc));
}

// ---------------------------------------------------------------------------
// Kernel 3: out = x * gate (gate broadcast over channels). float4 vectorized;
// HW_ = 3136 is divisible by 4 so a float4 never crosses an hw row of gate...
// (gate index only depends on b and hw; within a float4 the 4 hw are
// consecutive, so we need a float4 of gate too — gate is [B, HW], contiguous
// in hw, so that's a clean float4 load as well.)
// ---------------------------------------------------------------------------
#define HW4_ (HW_ / 4)  // 784
__global__ __launch_bounds__(256) void sa_mul_kernel(
    const float* __restrict__ x, const float* __restrict__ gate,
    float* __restrict__ out) {
  const long total4 = (long)B_ * C_ * HW4_;
  long i = (long)blockIdx.x * blockDim.x + threadIdx.x;
  if (i >= total4) return;
  const int hw4 = (int)(i % HW4_);
  const long bc = i / HW4_;
  const int b = (int)(bc / C_);

  float4 xv = ((const float4*)x)[i];
  float4 gv = ((const float4*)gate)[(long)b * HW4_ + hw4];
  float4 ov;
  ov.x = xv.x * gv.x;
  ov.y = xv.y * gv.y;
  ov.z = xv.z * gv.z;
  ov.w = xv.w * gv.w;
  ((float4*)out)[i] = ov;
}

extern "C" void kernel_launch(void* const* d_in, const int* in_sizes, int n_in,
                              void* d_out, int out_size, void* d_ws, size_t ws_size,
                              hipStream_t stream) {
  const float* x  = (const float*)d_in[0];   // [32,256,56,56]
  const float* wc = (const float*)d_in[1];   // [1,2,7,7]
  float* out = (float*)d_out;

  // Workspace carve-up: pool [B,2,HW] then gate [B,HW].
  float* pool = (float*)d_ws;                      // 32*2*3136*4 = 802,816 B
  float* gate = pool + (long)B_ * 2 * HW_;         // +32*3136*4 = 401,408 B

  // Kernel 1: channel reduce. 1568 blocks x 256.
  sa_reduce_kernel<<<BHW_ / 64, 256, 0, stream>>>(x, pool);

  // Kernel 2: conv + sigmoid. 100352 threads.
  sa_conv_kernel<<<(BHW_ + 255) / 256, 256, 0, stream>>>(pool, wc, gate);

  // Kernel 3: broadcast multiply. 6,422,528 float4 elements.
  const long total4 = (long)B_ * C_ * HW4_;
  sa_mul_kernel<<<(int)((total4 + 255) / 256), 256, 0, stream>>>(x, gate, out);
}

// Round 3
// 206.449 us; speedup vs baseline: 1.0173x; 1.0173x over previous
//
#include <hip/hip_runtime.h>
#include <math.h>

// Problem constants (x: [32, 256, 56, 56] fp32)
#define B_    32
#define C_    256
#define H_    56
#define W_    56
#define HW_   (H_ * W_)        // 3136
#define BHW_  (B_ * HW_)       // 100352
#define HW4_  (HW_ / 4)        // 784 float4 per (b,c) image plane
#define NF4_  (BHW_ / 4)       // 25088 global float4 positions per channel-plane set
#define CHUNKF4_ 32            // float4 per block chunk (128 floats)
#define NBLK_ (NF4_ / CHUNKF4_)  // 784 blocks for both kernels

typedef float f4v __attribute__((ext_vector_type(4)));

// ---------------------------------------------------------------------------
// Kernel 1: channel-wise mean + max -> pool [B, 2, HW] (avg plane, max plane).
// Block = 256 threads over a chunk of 32 consecutive global float4 positions
// (128 hw floats). f4-lane = t&31, channel group = t>>5 (8 groups x 32 ch).
// Per-lane b/hw4 from the global float4 index (chunks may straddle an image
// boundary; per-lane indexing keeps that correct). Wave loads: 2 x 512 B
// contiguous segments per instruction — fully coalesced.
// ---------------------------------------------------------------------------
__global__ __launch_bounds__(256) void sa_reduce_kernel(
    const float* __restrict__ x, float* __restrict__ pool) {
  const int t = threadIdx.x;
  const int lane = t & 31;        // f4 position within chunk
  const int cgrp = t >> 5;        // 0..7
  const unsigned if4 = (unsigned)blockIdx.x * CHUNKF4_ + lane;  // < 25088
  const unsigned b = if4 / HW4_;          // const-div -> magic mul
  const unsigned hw4 = if4 % HW4_;

  const f4v* x4 = (const f4v*)x;
  const unsigned base = (b * C_ + cgrp) * HW4_ + hw4;

  f4v s = {0.f, 0.f, 0.f, 0.f};
  f4v m = {-INFINITY, -INFINITY, -INFINITY, -INFINITY};
#pragma unroll 8
  for (int k = 0; k < 32; ++k) {
    f4v v = x4[base + (unsigned)(k * 8) * HW4_];  // c = cgrp + 8k
    s += v;
    m = (f4v){fmaxf(m.x, v.x), fmaxf(m.y, v.y), fmaxf(m.z, v.z), fmaxf(m.w, v.w)};
  }

  __shared__ f4v ssum[8][32];
  __shared__ f4v smax[8][32];
  ssum[cgrp][lane] = s;
  smax[cgrp][lane] = m;
  __syncthreads();

  if (t < 32) {
    f4v S = ssum[0][t];
    f4v M = smax[0][t];
#pragma unroll
    for (int g = 1; g < 8; ++g) {
      f4v sg = ssum[g][t];
      f4v mg = smax[g][t];
      S += sg;
      M = (f4v){fmaxf(M.x, mg.x), fmaxf(M.y, mg.y), fmaxf(M.z, mg.z), fmaxf(M.w, mg.w)};
    }
    f4v* p4 = (f4v*)pool;
    const unsigned jf4 = (unsigned)blockIdx.x * CHUNKF4_ + t;
    const unsigned bb = jf4 / HW4_;
    const unsigned hh = jf4 % HW4_;
    p4[bb * 2 * HW4_ + hh]        = S * (1.0f / (float)C_);  // avg plane
    p4[bb * 2 * HW4_ + HW4_ + hh] = M;                       // max plane
  }
}

// ---------------------------------------------------------------------------
// Kernel 2: fused 7x7 SAME conv (2->1) + sigmoid (into LDS) + broadcast apply.
// Same chunking as K1: block owns 128 consecutive hw floats (global).
// Phase A: 256 threads = 128 positions x 2 input channels; each computes a
//   49-tap partial from pool (L2-resident), pair-summed via LDS -> sigmoid ->
//   sgate[128] in LDS. Gate never touches global memory.
// Phase B: thread t -> f4 = t&31, cgrp = t>>5; loops 32 channels applying
//   gate (LDS float4, broadcast) to x with coalesced float4 load/store.
// ---------------------------------------------------------------------------
__global__ __launch_bounds__(256) void sa_conv_apply_kernel(
    const float* __restrict__ x, const float* __restrict__ pool,
    const float* __restrict__ wt, float* __restrict__ out) {
  const int t = threadIdx.x;

  __shared__ float partial[256];
  __shared__ f4v sgate4[CHUNKF4_];  // 128 gate floats

  // ---- Phase A: conv + sigmoid into LDS ----
  {
    const int pos = t >> 1;        // 0..127 local float position
    const int ic = t & 1;          // input channel (avg / max plane)
    const unsigned p = (unsigned)blockIdx.x * 128 + (unsigned)pos;  // < 100352
    const unsigned b = p / HW_;
    const unsigned hw = p % HW_;
    const int h = (int)(hw / W_);
    const int w = (int)(hw % W_);
    const float* pl = pool + ((long)b * 2 + ic) * HW_;
    const float* wr0 = wt + ic * 49;
    float acc = 0.f;
#pragma unroll
    for (int kh = 0; kh < 7; ++kh) {
      const int ih = h + kh - 3;
      if (ih < 0 || ih >= H_) continue;
      const float* row = pl + ih * W_;
      const float* wr = wr0 + kh * 7;
#pragma unroll
      for (int kw = 0; kw < 7; ++kw) {
        const int iw = w + kw - 3;
        if (iw < 0 || iw >= W_) continue;
        acc = fmaf(row[iw], wr[kw], acc);
      }
    }
    partial[t] = acc;
  }
  __syncthreads();
  if (t < 128) {
    float a = partial[2 * t] + partial[2 * t + 1];
    ((float*)sgate4)[t] = 1.0f / (1.0f + __expf(-a));
  }
  __syncthreads();

  // ---- Phase B: out = x * gate over 256 channels ----
  {
    const int lane = t & 31;
    const int cgrp = t >> 5;
    const unsigned if4 = (unsigned)blockIdx.x * CHUNKF4_ + lane;
    const unsigned b = if4 / HW4_;
    const unsigned hw4 = if4 % HW4_;
    const unsigned base = (b * C_ + cgrp) * HW4_ + hw4;
    const f4v* x4 = (const f4v*)x;
    f4v* o4 = (f4v*)out;
    const f4v g = sgate4[lane];
#pragma unroll 8
    for (int k = 0; k < 32; ++k) {
      const unsigned idx = base + (unsigned)(k * 8) * HW4_;  // c = cgrp + 8k
      f4v v = x4[idx];
      __builtin_nontemporal_store(v * g, &o4[idx]);
    }
  }
}

extern "C" void kernel_launch(void* const* d_in, const int* in_sizes, int n_in,
                              void* d_out, int out_size, void* d_ws, size_t ws_size,
                              hipStream_t stream) {
  const float* x  = (const float*)d_in[0];   // [32,256,56,56]
  const float* wc = (const float*)d_in[1];   // [1,2,7,7]
  float* out = (float*)d_out;
  float* pool = (float*)d_ws;                // [B,2,HW] = 802,816 B

  sa_reduce_kernel<<<NBLK_, 256, 0, stream>>>(x, pool);
  sa_conv_apply_kernel<<<NBLK_, 256, 0, stream>>>(x, pool, wc, out);
}